// Round 1
// baseline (323.768 us; speedup 1.0000x reference)
//
#include <hip/hip_runtime.h>
#include <math.h>

// Fixed problem dims from setup_inputs()
#define BATCH 2
#define C 64
#define HIN 128
#define WIN 128
#define OH 256
#define OW 256
#define SCALE 2.0f

__global__ __launch_bounds__(256) void scab_kernel(
    const float* __restrict__ x,    // (B, C, HIN, WIN)
    const float* __restrict__ wcm,  // weight_compress (4, 8, 64)
    const float* __restrict__ wex,  // weight_expand   (4, 64, 8)
    const float* __restrict__ w1,   // (64, 68)
    const float* __restrict__ b1,   // (64)
    const float* __restrict__ w2,   // (64, 64)
    const float* __restrict__ b2,   // (64)
    const float* __restrict__ wr,   // (4, 64)
    const float* __restrict__ br,   // (4)
    const float* __restrict__ wo,   // (2, 64)
    const float* __restrict__ bo,   // (2)
    float* __restrict__ out)        // (B, C, OH, OW)
{
    const int p  = blockIdx.x * 256 + threadIdx.x;
    const int ox = p & (OW - 1);
    const int oy = (p >> 8) & (OH - 1);
    const int bb = p >> 16;

    // ---- coords channels (match reference exactly) ----
    const float c01 = 1.0f / SCALE;
    const float fh = (oy + 0.5f) / SCALE;
    const float coor_h = fh - floorf(fh + 0.001f) - 0.5f;
    const float fw = (ox + 0.5f) / SCALE;
    const float coor_w = fw - floorf(fw + 0.001f) - 0.5f;

    // ---- base grid (make_grid without offset) ----
    const float gx = ((ox + 0.5f) / SCALE - 0.5f) * (2.0f / (WIN - 1)) - 1.0f;
    const float gy = ((oy + 0.5f) / SCALE - 0.5f) * (2.0f / (HIN - 1)) - 1.0f;

    const float* __restrict__ xb = x + bb * (C * HIN * WIN);

    // ================= sampling 1: pre_fea =================
    float pf[C];
    {
        const float fx = ((gx + 1.0f) * WIN - 1.0f) * 0.5f;
        const float fy = ((gy + 1.0f) * HIN - 1.0f) * 0.5f;
        const float x0 = floorf(fx), y0 = floorf(fy);
        const float wx1 = fx - x0, wx0 = 1.0f - wx1;
        const float wy1 = fy - y0, wy0 = 1.0f - wy1;
        const float x1 = x0 + 1.0f, y1 = y0 + 1.0f;
        const bool vx0 = (x0 >= 0.0f) && (x0 <= (float)(WIN - 1));
        const bool vx1 = (x1 >= 0.0f) && (x1 <= (float)(WIN - 1));
        const bool vy0 = (y0 >= 0.0f) && (y0 <= (float)(HIN - 1));
        const bool vy1 = (y1 >= 0.0f) && (y1 <= (float)(HIN - 1));
        const int xi0 = (int)fminf(fmaxf(x0, 0.0f), (float)(WIN - 1));
        const int xi1 = (int)fminf(fmaxf(x1, 0.0f), (float)(WIN - 1));
        const int yi0 = (int)fminf(fmaxf(y0, 0.0f), (float)(HIN - 1));
        const int yi1 = (int)fminf(fmaxf(y1, 0.0f), (float)(HIN - 1));
        const float w00 = wx0 * wy0 * ((vx0 && vy0) ? 1.0f : 0.0f);
        const float w10 = wx1 * wy0 * ((vx1 && vy0) ? 1.0f : 0.0f);
        const float w01 = wx0 * wy1 * ((vx0 && vy1) ? 1.0f : 0.0f);
        const float w11 = wx1 * wy1 * ((vx1 && vy1) ? 1.0f : 0.0f);
        const int i00 = yi0 * WIN + xi0;
        const int i10 = yi0 * WIN + xi1;
        const int i01 = yi1 * WIN + xi0;
        const int i11 = yi1 * WIN + xi1;
        #pragma unroll
        for (int c = 0; c < C; ++c) {
            const float* __restrict__ xc = xb + c * (HIN * WIN);
            pf[c] = xc[i00] * w00 + xc[i10] * w10 + xc[i01] * w01 + xc[i11] * w11;
        }
    }

    // ================= conv1 (68 -> 64) + ReLU =================
    float h1[C];
    #pragma unroll
    for (int o = 0; o < C; ++o) {
        const float* __restrict__ wrow = w1 + o * (C + 4);
        float acc = b1[o];
        acc = fmaf(wrow[0], c01, acc);
        acc = fmaf(wrow[1], c01, acc);
        acc = fmaf(wrow[2], coor_h, acc);
        acc = fmaf(wrow[3], coor_w, acc);
        #pragma unroll
        for (int c = 0; c < C; ++c) acc = fmaf(wrow[4 + c], pf[c], acc);
        h1[o] = fmaxf(acc, 0.0f);
    }

    // ================= conv2 (64 -> 64) + ReLU =================
    float emb[C];
    #pragma unroll
    for (int o = 0; o < C; ++o) {
        const float* __restrict__ wrow = w2 + o * C;
        float acc = b2[o];
        #pragma unroll
        for (int c = 0; c < C; ++c) acc = fmaf(wrow[c], h1[c], acc);
        emb[o] = fmaxf(acc, 0.0f);
    }

    // ================= offset head (2) + gate head (4) =================
    float offx = bo[0], offy = bo[1];
    float z0 = br[0], z1 = br[1], z2 = br[2], z3 = br[3];
    #pragma unroll
    for (int c = 0; c < C; ++c) {
        const float e = emb[c];
        offx = fmaf(wo[c],         e, offx);
        offy = fmaf(wo[C + c],     e, offy);
        z0   = fmaf(wr[c],         e, z0);
        z1   = fmaf(wr[C + c],     e, z1);
        z2   = fmaf(wr[2 * C + c], e, z2);
        z3   = fmaf(wr[3 * C + c], e, z3);
    }
    float rg[4];
    rg[0] = 1.0f / (1.0f + __expf(-z0));
    rg[1] = 1.0f / (1.0f + __expf(-z1));
    rg[2] = 1.0f / (1.0f + __expf(-z2));
    rg[3] = 1.0f / (1.0f + __expf(-z3));

    // ================= sampling 2: fea0 (with offset) =================
    float fea0[C];
    {
        const float ix2 = gx + offx * (2.0f / (WIN - 1));
        const float iy2 = gy + offy * (2.0f / (HIN - 1));
        const float fx = ((ix2 + 1.0f) * WIN - 1.0f) * 0.5f;
        const float fy = ((iy2 + 1.0f) * HIN - 1.0f) * 0.5f;
        const float x0 = floorf(fx), y0 = floorf(fy);
        const float wx1 = fx - x0, wx0 = 1.0f - wx1;
        const float wy1 = fy - y0, wy0 = 1.0f - wy1;
        const float x1 = x0 + 1.0f, y1 = y0 + 1.0f;
        const bool vx0 = (x0 >= 0.0f) && (x0 <= (float)(WIN - 1));
        const bool vx1 = (x1 >= 0.0f) && (x1 <= (float)(WIN - 1));
        const bool vy0 = (y0 >= 0.0f) && (y0 <= (float)(HIN - 1));
        const bool vy1 = (y1 >= 0.0f) && (y1 <= (float)(HIN - 1));
        const int xi0 = (int)fminf(fmaxf(x0, 0.0f), (float)(WIN - 1));
        const int xi1 = (int)fminf(fmaxf(x1, 0.0f), (float)(WIN - 1));
        const int yi0 = (int)fminf(fmaxf(y0, 0.0f), (float)(HIN - 1));
        const int yi1 = (int)fminf(fmaxf(y1, 0.0f), (float)(HIN - 1));
        const float w00 = wx0 * wy0 * ((vx0 && vy0) ? 1.0f : 0.0f);
        const float w10 = wx1 * wy0 * ((vx1 && vy0) ? 1.0f : 0.0f);
        const float w01 = wx0 * wy1 * ((vx0 && vy1) ? 1.0f : 0.0f);
        const float w11 = wx1 * wy1 * ((vx1 && vy1) ? 1.0f : 0.0f);
        const int i00 = yi0 * WIN + xi0;
        const int i10 = yi0 * WIN + xi1;
        const int i01 = yi1 * WIN + xi0;
        const int i11 = yi1 * WIN + xi1;
        #pragma unroll
        for (int c = 0; c < C; ++c) {
            const float* __restrict__ xc = xb + c * (HIN * WIN);
            fea0[c] = xc[i00] * w00 + xc[i10] * w10 + xc[i01] * w01 + xc[i11] * w11;
        }
    }

    // ================= compress: comp[d] = sum_e r[e] * sum_c wc[e,d,c]*fea0[c] =================
    float comp[8];
    #pragma unroll
    for (int d = 0; d < 8; ++d) comp[d] = 0.0f;
    #pragma unroll
    for (int e = 0; e < 4; ++e) {
        const float re = rg[e];
        #pragma unroll
        for (int d = 0; d < 8; ++d) {
            const float* __restrict__ wrow = wcm + (e * 8 + d) * C;
            float acc = 0.0f;
            #pragma unroll
            for (int c = 0; c < C; ++c) acc = fmaf(wrow[c], fea0[c], acc);
            comp[d] = fmaf(re, acc, comp[d]);
        }
    }

    // ================= expand + residual: out[c] = fea0[c] + sum_e r[e]*sum_d we[e,c,d]*comp[d] =================
    float* __restrict__ ob = out + bb * (C * OH * OW) + oy * OW + ox;
    #pragma unroll
    for (int c = 0; c < C; ++c) {
        float acc = 0.0f;
        #pragma unroll
        for (int e = 0; e < 4; ++e) {
            const float* __restrict__ wrow = wex + (e * C + c) * 8;
            float s = 0.0f;
            #pragma unroll
            for (int d = 0; d < 8; ++d) s = fmaf(wrow[d], comp[d], s);
            acc = fmaf(rg[e], s, acc);
        }
        ob[c * (OH * OW)] = acc + fea0[c];
    }
}

extern "C" void kernel_launch(void* const* d_in, const int* in_sizes, int n_in,
                              void* d_out, int out_size, void* d_ws, size_t ws_size,
                              hipStream_t stream) {
    const float* x   = (const float*)d_in[0];
    const float* wcm = (const float*)d_in[1];
    const float* wex = (const float*)d_in[2];
    const float* w1  = (const float*)d_in[3];
    const float* b1  = (const float*)d_in[4];
    const float* w2  = (const float*)d_in[5];
    const float* b2  = (const float*)d_in[6];
    const float* wr  = (const float*)d_in[7];
    const float* br  = (const float*)d_in[8];
    const float* wo  = (const float*)d_in[9];
    const float* bo  = (const float*)d_in[10];
    float* out = (float*)d_out;

    const int total = BATCH * OH * OW;           // 131072 pixels
    const int blocks = total / 256;              // 512
    scab_kernel<<<blocks, 256, 0, stream>>>(x, wcm, wex, w1, b1, w2, b2,
                                            wr, br, wo, bo, out);
}